// Round 5
// baseline (309.128 us; speedup 1.0000x reference)
//
#include <hip/hip_runtime.h>
#include <stdint.h>

#define AS1 __attribute__((address_space(1)))
#define AS3 __attribute__((address_space(3)))

typedef __bf16 bf16x8 __attribute__((ext_vector_type(8)));
typedef float f32x16 __attribute__((ext_vector_type(16)));

__device__ __forceinline__ unsigned short f2bf(float f) {
  unsigned u = __float_as_uint(f);
  u += 0x7FFF + ((u >> 16) & 1);   // round-to-nearest-even
  return (unsigned short)(u >> 16);
}

// ---------------- merged fp32 -> bf16 cast for X, W_in, W_out (grid-stride) ----------------
__global__ __launch_bounds__(256) void cast_all_kernel(const float* __restrict__ X,
                                                       const float* __restrict__ Wi,
                                                       const float* __restrict__ Wo,
                                                       unsigned short* __restrict__ out) {
  const int c1 = 2097152;            // X groups of 4
  const int c2 = 786432;             // W_in groups
  const int c3 = 262144;             // W_out groups
  const int total = c1 + c2 + c3;
  for (int i = blockIdx.x * 256 + threadIdx.x; i < total; i += 2048 * 256) {
    const float* src;
    int j = i;
    if (i < c1) src = X;
    else if (i < c1 + c2) { src = Wi; j = i - c1; }
    else { src = Wo; j = i - c1 - c2; }
    float4 v = reinterpret_cast<const float4*>(src)[j];
    ushort4 o;
    o.x = f2bf(v.x); o.y = f2bf(v.y); o.z = f2bf(v.z); o.w = f2bf(v.w);
    reinterpret_cast<ushort4*>(out)[i] = o;
  }
}

// ================= gemm8p: 256x256, BK=32, 4-slot ring, TRUE phased schedule =================
// 512 threads = 8 waves (2M x 4N), per-wave C = 128x64 as 4(m) x 2(n) 32x32x16 frags.
// Iteration = 2 K-tiles (slots t&3), 4 phases. Each phase:
//   {ds_read subtile || 2 global_load_lds} -> barrier -> lgkm(0) -> prio1 -> 8 MFMA -> prio0 -> barrier
// Staging: tile t0+3 during P0(A)/P1(B), tile t0+4 during P2(A)/P3(B).
//   Slot safety: (t0+3)&3 = slot of tile t0-1 whose reads finished at prev-iter P3 exit barrier;
//   (t0+4)&3 = slot of tile t0 whose reads finish at P1 exit barrier (stage issued in P2/P3).
// Counted waits (before a barrier, so the collective guarantee holds):
//   P1-exit vmcnt(8): tiles <= t0+1 landed (allowed in flight: t0+2 [4] + t0+3 [4]).
//   P3-exit vmcnt(8): tiles <= t0+2 landed (allowed: t0+3 [4] + t0+4 [4]).
//   Tail: counts shrink exactly with skipped stages (8 -> 4/0) to keep the guarantee.
// MODE 1: bf16 out, +bias; blocks bx>=8 write V^T into vt  (QKV + transpose)
// MODE 2: bf16 out = exp((mask? -1e20 : val)/32); fp32 row sums atomically into sums
template<int MODE>
__global__ __launch_bounds__(512, 2) void gemm8p(
    const unsigned short* __restrict__ A, long lda, long strideA,
    const unsigned short* __restrict__ B, long ldb, long strideB,
    void* __restrict__ Cv, long ldc, long strideC,
    const float* __restrict__ bias, const int* __restrict__ mask,
    float* __restrict__ sums, unsigned short* __restrict__ vt, int K) {
  __shared__ unsigned short sAll[65536];   // 128 KB: 4 slots x 32 KB (A 16KB | B 16KB)
  char* sBase = (char*)sAll;
  const int t = threadIdx.x;
  const int lane = t & 63;
  const int wave = t >> 6;

  // T1: XCD-aware bijective block swizzle (nwg % 8 == 0 for all our grids)
  const int nx = gridDim.x;
  const int nwg = nx * gridDim.y;
  int orig = blockIdx.y * nx + blockIdx.x;
  int q = nwg >> 3, r8 = nwg & 7;
  int xcd = orig & 7, idx = orig >> 3;
  int wg = (xcd < r8 ? xcd * (q + 1) : r8 * (q + 1) + (xcd - r8) * q) + idx;
  const int bx = wg % nx, by = wg / nx, bz = blockIdx.z;

  const unsigned short* Ab = A + (size_t)bz * strideA + (size_t)by * 256 * lda;
  const unsigned short* Bb = B + (size_t)bz * strideB + (size_t)bx * 256 * ldb;

  // staging (R3-verified conflict-free): rows of 32 bf16 (64 B = 4 chunks of 16 B).
  // dest linear; SOURCE chunk pre-swizzled: LDS slot c of row r = src chunk c ^ ((r>>2)&3).
  const int srow = t >> 2;                                  // 0..127
  const int scol = ((t & 3) ^ ((srow >> 2) & 3)) << 3;      // elems
  const unsigned short* aS = Ab + (size_t)srow * lda + scol;
  const unsigned short* bS = Bb + (size_t)srow * ldb + scol;

  auto stageA = [&](int tk) {
    char* base = sBase + (tk & 3) * 32768 + wave * 1024;
    const unsigned short* ap = aS + tk * 32;
#pragma unroll
    for (int l = 0; l < 2; l++)
      __builtin_amdgcn_global_load_lds((AS1 void*)(ap + (size_t)(l * 128) * lda),
                                       (AS3 void*)(base + l * 8192), 16, 0, 0);
  };
  auto stageB = [&](int tk) {
    char* base = sBase + (tk & 3) * 32768 + 16384 + wave * 1024;
    const unsigned short* bp = bS + tk * 32;
#pragma unroll
    for (int l = 0; l < 2; l++)
      __builtin_amdgcn_global_load_lds((AS1 void*)(bp + (size_t)(l * 128) * ldb),
                                       (AS3 void*)(base + l * 8192), 16, 0, 0);
  };

  const int NT = K >> 5;          // K/32 tiles; NT even (K=1024 here)
  const int NTH = NT >> 1;

  f32x16 acc[4][2];
#pragma unroll
  for (int i = 0; i < 4; i++)
#pragma unroll
    for (int j = 0; j < 2; j++)
#pragma unroll
      for (int r = 0; r < 16; r++) acc[i][j][r] = 0.f;

  const int wm = (wave >> 2) << 7;   // 0 / 128
  const int wn = (wave & 3) << 6;    // 0 / 64 / 128 / 192
  const int r31 = lane & 31;
  const int half = lane >> 5;
  const int swz = (r31 >> 2) & 3;
  int offC[2];
#pragma unroll
  for (int ks = 0; ks < 2; ks++)
    offC[ks] = ((((ks << 1) + half) ^ swz) << 4);
  int rowA[4], rowB[2];
#pragma unroll
  for (int i = 0; i < 4; i++) rowA[i] = (wm + 32 * i + r31) << 6;
#pragma unroll
  for (int j = 0; j < 2; j++) rowB[j] = (wn + 32 * j + r31) << 6;

  auto RD2 = [&](bf16x8 (&d)[2], const char* s, int row) {
    d[0] = *reinterpret_cast<const bf16x8*>(s + row + offC[0]);
    d[1] = *reinterpret_cast<const bf16x8*>(s + row + offC[1]);
  };
  auto MF8 = [&](f32x16& c00, f32x16& c01, f32x16& c10, f32x16& c11,
                 bf16x8 (&xa)[2], bf16x8 (&xb)[2], bf16x8 (&b0)[2], bf16x8 (&b1)[2]) {
#pragma unroll
    for (int ks = 0; ks < 2; ks++) {
      c00 = __builtin_amdgcn_mfma_f32_32x32x16_bf16(xa[ks], b0[ks], c00, 0, 0, 0);
      c01 = __builtin_amdgcn_mfma_f32_32x32x16_bf16(xa[ks], b1[ks], c01, 0, 0, 0);
      c10 = __builtin_amdgcn_mfma_f32_32x32x16_bf16(xb[ks], b0[ks], c10, 0, 0, 0);
      c11 = __builtin_amdgcn_mfma_f32_32x32x16_bf16(xb[ks], b1[ks], c11, 0, 0, 0);
    }
  };

#define SB0 __builtin_amdgcn_sched_barrier(0)
#define BAR __builtin_amdgcn_s_barrier()
#define LGKM0 asm volatile("s_waitcnt lgkmcnt(0)" ::: "memory")

  // prologue: stage tiles 0,1,2 (12 loads/wave); wait oldest 4 (tile 0), 8 stay in flight
  stageA(0); stageB(0);
  stageA(1); stageB(1);
  stageA(2); stageB(2);
  asm volatile("s_waitcnt vmcnt(8)" ::: "memory");
  SB0; BAR; SB0;

  for (int it = 0; it < NTH; ++it) {
    const int t0 = 2 * it, t1 = t0 + 1;
    const char* sa0 = sBase + (t0 & 3) * 32768; const char* sb0 = sa0 + 16384;
    const char* sa1 = sBase + (t1 & 3) * 32768; const char* sb1 = sa1 + 16384;
    const int tS0 = t0 + 3, tS1 = t0 + 4;
    bf16x8 bq0[2], bq1[2], a0[2], a1[2];

    // ---- P0: slot t0: B all + A m0,m1 ; stage A(t0+3)
    RD2(bq0, sb0, rowB[0]); RD2(bq1, sb0, rowB[1]);
    RD2(a0, sa0, rowA[0]);  RD2(a1, sa0, rowA[1]);
    if (tS0 < NT) stageA(tS0);
    SB0; BAR; LGKM0; SB0;
    __builtin_amdgcn_s_setprio(1);
    MF8(acc[0][0], acc[0][1], acc[1][0], acc[1][1], a0, a1, bq0, bq1);
    __builtin_amdgcn_s_setprio(0);
    SB0; BAR; SB0;

    // ---- P1: slot t0: A m2,m3 ; stage B(t0+3) ; exit vmcnt -> tiles <= t0+1 landed
    RD2(a0, sa0, rowA[2]); RD2(a1, sa0, rowA[3]);
    if (tS0 < NT) stageB(tS0);
    SB0; BAR; LGKM0; SB0;
    __builtin_amdgcn_s_setprio(1);
    MF8(acc[2][0], acc[2][1], acc[3][0], acc[3][1], a0, a1, bq0, bq1);
    __builtin_amdgcn_s_setprio(0);
    SB0;
    if (tS0 < NT) { asm volatile("s_waitcnt vmcnt(8)" ::: "memory"); }
    else          { asm volatile("s_waitcnt vmcnt(0)" ::: "memory"); }
    SB0; BAR; SB0;

    // ---- P2: slot t1: B all + A m0,m1 ; stage A(t0+4)
    RD2(bq0, sb1, rowB[0]); RD2(bq1, sb1, rowB[1]);
    RD2(a0, sa1, rowA[0]);  RD2(a1, sa1, rowA[1]);
    if (tS1 < NT) stageA(tS1);
    SB0; BAR; LGKM0; SB0;
    __builtin_amdgcn_s_setprio(1);
    MF8(acc[0][0], acc[0][1], acc[1][0], acc[1][1], a0, a1, bq0, bq1);
    __builtin_amdgcn_s_setprio(0);
    SB0; BAR; SB0;

    // ---- P3: slot t1: A m2,m3 ; stage B(t0+4) ; exit vmcnt -> tiles <= t0+2 landed
    RD2(a0, sa1, rowA[2]); RD2(a1, sa1, rowA[3]);
    if (tS1 < NT) stageB(tS1);
    SB0; BAR; LGKM0; SB0;
    __builtin_amdgcn_s_setprio(1);
    MF8(acc[2][0], acc[2][1], acc[3][0], acc[3][1], a0, a1, bq0, bq1);
    __builtin_amdgcn_s_setprio(0);
    SB0;
    if (it < NTH - 1) {
      if (tS1 < NT) { asm volatile("s_waitcnt vmcnt(8)" ::: "memory"); }
      else          { asm volatile("s_waitcnt vmcnt(4)" ::: "memory"); }
      SB0; BAR; SB0;
    }
  }
#undef SB0
#undef BAR
#undef LGKM0

  // ---- epilogue (verified layout: col = lane&31 -> n, row = (r&3)+8*(r>>2)+4*half) ----
  const int* mrow = (MODE == 2) ? (mask + (size_t)bz * 2048) : nullptr;
  const bool vblock = (MODE == 1) && (bx >= 8);  // QKV: n>=2048 is the V third

#pragma unroll
  for (int i = 0; i < 4; i++) {
    int gmb = by * 256 + wm + i * 32;
    float rs[16];
    if (MODE == 2) {
#pragma unroll
      for (int r = 0; r < 16; r++) rs[r] = 0.f;
    }
#pragma unroll
    for (int j = 0; j < 2; j++) {
      int gn = bx * 256 + wn + j * 32 + r31;
      float bv = (MODE == 1) ? bias[gn] : 0.0f;
      if (MODE == 1 && vblock) {
        // write V^T: Vt[b][d][s], d = gn-2048, s = gmb+row
        int b = gmb >> 11;
        int sbase = gmb & 2047;
        int d = gn - 2048;
        unsigned short* vp = vt + (size_t)b * 1024 * 2048 + (size_t)d * 2048 + sbase + 4 * half;
#pragma unroll
        for (int qd = 0; qd < 4; qd++) {
          ushort4 o;
          o.x = f2bf(acc[i][j][4 * qd + 0] + bv);
          o.y = f2bf(acc[i][j][4 * qd + 1] + bv);
          o.z = f2bf(acc[i][j][4 * qd + 2] + bv);
          o.w = f2bf(acc[i][j][4 * qd + 3] + bv);
          *reinterpret_cast<ushort4*>(vp + 8 * qd) = o;
        }
      } else {
        bool msk = (MODE == 2) ? (mrow[gn] == 0) : false;
#pragma unroll
        for (int r = 0; r < 16; r++) {
          int row = (r & 3) + 8 * (r >> 2) + 4 * half;
          float val = acc[i][j][r] + bv;
          size_t off = (size_t)bz * strideC + (size_t)(gmb + row) * ldc + gn;
          if (MODE == 2) {
            if (msk) val = -1e20f;
            val = __expf(val * 0.03125f);  // mask BEFORE 1/sqrt(1024) scale, per ref
            rs[r] += val;
            ((unsigned short*)Cv)[off] = f2bf(val);
          } else {
            ((unsigned short*)Cv)[off] = f2bf(val);
          }
        }
      }
    }
    if (MODE == 2) {
      float* srowp = sums + (size_t)bz * 2048;
#pragma unroll
      for (int r = 0; r < 16; r++) {
        float v = rs[r];
#pragma unroll
        for (int o = 16; o >= 1; o >>= 1) v += __shfl_xor(v, o, 64);
        if (r31 == 0) {
          int row = (r & 3) + 8 * (r >> 2) + 4 * half;
          atomicAdd(&srowp[gmb + row], v);
        }
      }
    }
  }
}

// ================= proven 128x128 kernel (R4: conflict-free swizzle) for PV + out-proj =================
template<int MODE>
__global__ __launch_bounds__(256, 2) void gemm_bt128(
    const unsigned short* __restrict__ A, long lda, long strideA,
    const unsigned short* __restrict__ B, long ldb, long strideB,
    void* __restrict__ Cv, long ldc, long strideC,
    const float* __restrict__ bias, const int* __restrict__ mask,
    float* __restrict__ sums, unsigned short* __restrict__ vt, int K) {
  __shared__ unsigned short sA[128 * 64];
  __shared__ unsigned short sB[128 * 64];
  const int t = threadIdx.x;
  const int lane = t & 63;
  const int wave = t >> 6;

  const unsigned short* Ab = A + (size_t)blockIdx.z * strideA + (size_t)blockIdx.y * 128 * lda;
  const unsigned short* Bb = B + (size_t)blockIdx.z * strideB + (size_t)blockIdx.x * 128 * ldb;

  const int srow = t >> 3;
  const int schunk = (t & 7) ^ ((srow >> 1) & 7);   // conflict-free row-pair swizzle
  const unsigned short* aptr = Ab + (size_t)srow * lda + schunk * 8;
  const unsigned short* bptr = Bb + (size_t)srow * ldb + schunk * 8;
  char* ldsA0 = (char*)&sA[0] + wave * 1024;
  char* ldsB0 = (char*)&sB[0] + wave * 1024;

  f32x16 acc[2][2];
#pragma unroll
  for (int i = 0; i < 2; i++)
#pragma unroll
    for (int j = 0; j < 2; j++)
#pragma unroll
      for (int r = 0; r < 16; r++) acc[i][j][r] = 0.f;

  const int wm = (wave >> 1) * 64;
  const int wn = (wave & 1) * 64;
  const int r31 = lane & 31;
  const int half = lane >> 5;
  const int swz = (r31 >> 1) & 7;

  int offA[2][4], offB[2][4];
#pragma unroll
  for (int i = 0; i < 2; i++)
#pragma unroll
    for (int s = 0; s < 4; s++) {
      offA[i][s] = (wm + i * 32 + r31) * 128 + (((2 * s + half) ^ swz) * 16);
      offB[i][s] = (wn + i * 32 + r31) * 128 + (((2 * s + half) ^ swz) * 16);
    }

  for (int k0 = 0; k0 < K; k0 += 64) {
    __syncthreads();
#pragma unroll
    for (int o = 0; o < 4; o++) {
      __builtin_amdgcn_global_load_lds((AS1 void*)(aptr + (size_t)o * 32 * lda + k0),
                                       (AS3 void*)(ldsA0 + o * 4096), 16, 0, 0);
      __builtin_amdgcn_global_load_lds((AS1 void*)(bptr + (size_t)o * 32 * ldb + k0),
                                       (AS3 void*)(ldsB0 + o * 4096), 16, 0, 0);
    }
    __syncthreads();
#pragma unroll
    for (int s = 0; s < 4; s++) {
      bf16x8 af[2], bfv[2];
#pragma unroll
      for (int i = 0; i < 2; i++) {
        af[i]  = *reinterpret_cast<const bf16x8*>((const char*)sA + offA[i][s]);
        bfv[i] = *reinterpret_cast<const bf16x8*>((const char*)sB + offB[i][s]);
      }
#pragma unroll
      for (int i = 0; i < 2; i++)
#pragma unroll
        for (int j = 0; j < 2; j++)
          acc[i][j] = __builtin_amdgcn_mfma_f32_32x32x16_bf16(af[i], bfv[j], acc[i][j], 0, 0, 0);
    }
  }

  // ---- epilogue ----
#pragma unroll
  for (int i = 0; i < 2; i++) {
    int gmb = blockIdx.y * 128 + wm + i * 32;
    float inv_r[16];
    if (MODE == 3) {
#pragma unroll
      for (int r = 0; r < 16; r++) {
        int row = (r & 3) + 8 * (r >> 2) + 4 * half;
        inv_r[r] = 1.0f / sums[(size_t)blockIdx.z * 2048 + gmb + row];
      }
    }
#pragma unroll
    for (int j = 0; j < 2; j++) {
      int gn = blockIdx.x * 128 + wn + j * 32 + r31;
      float bv = (MODE == 0) ? bias[gn] : 0.0f;
#pragma unroll
      for (int r = 0; r < 16; r++) {
        int row = (r & 3) + 8 * (r >> 2) + 4 * half;
        float val = acc[i][j][r] + bv;
        size_t off = (size_t)blockIdx.z * strideC + (size_t)(gmb + row) * ldc + gn;
        if (MODE == 3) {
          ((unsigned short*)Cv)[off] = f2bf(val * inv_r[r]);
        } else {
          ((float*)Cv)[off] = val;
        }
      }
    }
  }
}

extern "C" void kernel_launch(void* const* d_in, const int* in_sizes, int n_in,
                              void* d_out, int out_size, void* d_ws, size_t ws_size,
                              hipStream_t stream) {
  const float* X = (const float*)d_in[0];
  const int* mask = (const int*)d_in[1];
  const float* W_in = (const float*)d_in[2];
  const float* b_in = (const float*)d_in[3];
  const float* W_out = (const float*)d_in[4];
  const float* b_out = (const float*)d_in[5];
  float* out = (float*)d_out;

  const int S = 2048, D = 1024;
  // ws layout (bytes):
  //   Xb  [8192x1024] bf16  16777216  (reused as Ob after QKV)
  //   Wib [3072x1024] bf16   6291456
  //   Wob [1024x1024] bf16   2097152
  //   QK  [8192x2048] bf16  33554432  (Q cols 0..1023, K cols 1024..2047)
  //   P   [4x2048x2048] bf16 33554432 (unnormalized exp weights)
  //   Vt  [4x1024x2048] bf16 16777216
  //   sums[8192] f32            32768
  char* w = (char*)d_ws;
  unsigned short* Xb  = (unsigned short*)w;
  unsigned short* Wib = (unsigned short*)(w + 16777216);
  unsigned short* Wob = (unsigned short*)(w + 16777216 + 6291456);
  unsigned short* QK  = (unsigned short*)(w + 25165824);
  unsigned short* P   = (unsigned short*)(w + 58720256);
  unsigned short* Vt  = (unsigned short*)(w + 92274688);
  float*          sums = (float*)(w + 109051904);
  unsigned short* Ob  = Xb;

  // zero the row-sum accumulators (ws is re-poisoned before every call)
  hipMemsetAsync(sums, 0, 8192 * sizeof(float), stream);

  // one merged cast: X, W_in, W_out -> bf16 (outputs contiguous), grid-stride
  cast_all_kernel<<<2048, 256, 0, stream>>>(X, W_in, W_out, Xb);

  // QKV = Xb @ W_in^T + b_in; Q,K -> QK[8192x2048], V -> Vt (transposed in epilogue)
  // 256x256 phased: grid 12 x 32 = 384 blocks
  gemm8p<1><<<dim3(12, 32, 1), 512, 0, stream>>>(
      Xb, D, 0, Wib, D, 0, QK, 2048, 0, b_in, nullptr, nullptr, Vt, D);
  // P = exp(mask(Q K^T)/32); sums += fp32 row sums   [per batch 2048x2048]
  // 256x256 phased: grid 8 x 8 x 4 = 256 blocks
  gemm8p<2><<<dim3(8, 8, 4), 512, 0, stream>>>(
      QK, 2048, (long)S * 2048, QK + 1024, 2048, (long)S * 2048,
      P, S, (long)S * S, nullptr, mask, sums, nullptr, D);
  // O = (P @ Vt^T) / sums   [per batch 2048x1024] bf16
  gemm_bt128<3><<<dim3(8, 16, 4), 256, 0, stream>>>(
      P, S, (long)S * S, Vt, S, (long)D * S,
      Ob, D, (long)S * D, nullptr, nullptr, sums, nullptr, S);
  // out = O @ W_out^T + b_out  [8192x1024] fp32
  gemm_bt128<0><<<dim3(8, 64, 1), 256, 0, stream>>>(
      Ob, D, 0, Wob, D, 0, out, D, 0, b_out, nullptr, nullptr, nullptr, D);
}

// Round 6
// 296.735 us; speedup vs baseline: 1.0418x; 1.0418x over previous
//
#include <hip/hip_runtime.h>
#include <stdint.h>

#define AS1 __attribute__((address_space(1)))
#define AS3 __attribute__((address_space(3)))

typedef __bf16 bf16x8 __attribute__((ext_vector_type(8)));
typedef float f32x16 __attribute__((ext_vector_type(16)));

__device__ __forceinline__ unsigned short f2bf(float f) {
  unsigned u = __float_as_uint(f);
  u += 0x7FFF + ((u >> 16) & 1);   // round-to-nearest-even
  return (unsigned short)(u >> 16);
}

// ---------------- merged fp32 -> bf16 cast for X, W_in, W_out (grid-stride) ----------------
__global__ __launch_bounds__(256) void cast_all_kernel(const float* __restrict__ X,
                                                       const float* __restrict__ Wi,
                                                       const float* __restrict__ Wo,
                                                       unsigned short* __restrict__ out) {
  const int c1 = 2097152;            // X groups of 4
  const int c2 = 786432;             // W_in groups
  const int c3 = 262144;             // W_out groups
  const int total = c1 + c2 + c3;
  for (int i = blockIdx.x * 256 + threadIdx.x; i < total; i += 2048 * 256) {
    const float* src;
    int j = i;
    if (i < c1) src = X;
    else if (i < c1 + c2) { src = Wi; j = i - c1; }
    else { src = Wo; j = i - c1 - c2; }
    float4 v = reinterpret_cast<const float4*>(src)[j];
    ushort4 o;
    o.x = f2bf(v.x); o.y = f2bf(v.y); o.z = f2bf(v.z); o.w = f2bf(v.w);
    reinterpret_cast<ushort4*>(out)[i] = o;
  }
}

// ---------------- GEMM-BT 128x128, BK=128 (halved drain count), conflict-free swizzle ----------------
// C[m][n] = sum_k A[m][k]*B[n][k]. 4 waves of 2x2 32x32x16 MFMA.
// BK=128: 8 K-steps for K=1024 (was 16) -> half the barrier+vmcnt(0) drains per block.
// LDS 64 KB (A 32 + B 32), 2 blocks/CU preserved.
// Swizzle: canonical key(row) = (row>>1)&7 on 16-B chunks; stage source pre-swizzled,
// read XORs the same key -> involution; 16-lane groups touch 8 distinct chunks
// (adjacent lanes broadcast) = 32 banks exactly once -> conflict-free (R3: measured 0).
// T1: XCD-chunked bijective block swizzle on (bx,by) (nwg % 8 == 0 for all grids).
// MODE 0: fp32 out, +bias                                  (out-proj)
// MODE 1: bf16 out, +bias; blocks bx>=16 write V^T into vt (QKV + transpose)
// MODE 2: bf16 out = exp((mask? -1e20 : val)/32); fp32 row sums atomically into sums
// MODE 3: bf16 out = val / sums[row]                       (PV + softmax normalize)
template<int MODE>
__global__ __launch_bounds__(256, 2) void gemm_bt128(
    const unsigned short* __restrict__ A, long lda, long strideA,
    const unsigned short* __restrict__ B, long ldb, long strideB,
    void* __restrict__ Cv, long ldc, long strideC,
    const float* __restrict__ bias, const int* __restrict__ mask,
    float* __restrict__ sums, unsigned short* __restrict__ vt, int K) {
  __shared__ unsigned short sA[128 * 128];   // 32 KB
  __shared__ unsigned short sB[128 * 128];   // 32 KB
  const int t = threadIdx.x;
  const int lane = t & 63;
  const int wave = t >> 6;

  // T1: XCD-chunked bijective swizzle of (bx,by); bz untouched
  const int nx = gridDim.x;
  const int nwg = nx * gridDim.y;           // multiple of 8 for all our grids
  const int orig = blockIdx.y * nx + blockIdx.x;
  const int qc = nwg >> 3;
  const int wg = (orig & 7) * qc + (orig >> 3);
  const int bx = wg % nx, by = wg / nx, bz = blockIdx.z;

  const unsigned short* Ab = A + (size_t)bz * strideA + (size_t)by * 128 * lda;
  const unsigned short* Bb = B + (size_t)bz * strideB + (size_t)bx * 128 * ldb;

  // staging: rows of 128 bf16 = 256 B = 16 chunks of 16 B. thread t -> row t>>4 (+o*16),
  // chunk (t&15) pre-swizzled by key(row)=(row>>1)&7 (o*16 doesn't perturb bits 1-3).
  const int srow = t >> 4;                                  // 0..15
  const int schunk = (t & 15) ^ ((srow >> 1) & 7);
  const unsigned short* aptr = Ab + (size_t)srow * lda + schunk * 8;
  const unsigned short* bptr = Bb + (size_t)srow * ldb + schunk * 8;
  char* ldsA0 = (char*)&sA[0] + wave * 1024;   // wave-linear dest: + o*4096
  char* ldsB0 = (char*)&sB[0] + wave * 1024;

  f32x16 acc[2][2];
#pragma unroll
  for (int i = 0; i < 2; i++)
#pragma unroll
    for (int j = 0; j < 2; j++)
#pragma unroll
      for (int r = 0; r < 16; r++) acc[i][j][r] = 0.f;

  const int wm = (wave >> 1) * 64;
  const int wn = (wave & 1) * 64;
  const int r31 = lane & 31;
  const int half = lane >> 5;
  const int swz = (r31 >> 1) & 7;   // key(row): bits 1-3 of row == bits 1-3 of r31

  int chunkOff[8];
#pragma unroll
  for (int s = 0; s < 8; s++) chunkOff[s] = (((2 * s + half) ^ swz) << 4);
  int rowA[2], rowB[2];
#pragma unroll
  for (int i = 0; i < 2; i++) {
    rowA[i] = (wm + i * 32 + r31) << 8;   // *256 B per row
    rowB[i] = (wn + i * 32 + r31) << 8;
  }

  for (int k0 = 0; k0 < K; k0 += 128) {
    __syncthreads();
#pragma unroll
    for (int o = 0; o < 8; o++) {
      __builtin_amdgcn_global_load_lds((AS1 void*)(aptr + (size_t)o * 16 * lda + k0),
                                       (AS3 void*)(ldsA0 + o * 4096), 16, 0, 0);
      __builtin_amdgcn_global_load_lds((AS1 void*)(bptr + (size_t)o * 16 * ldb + k0),
                                       (AS3 void*)(ldsB0 + o * 4096), 16, 0, 0);
    }
    __syncthreads();
#pragma unroll
    for (int s = 0; s < 8; s++) {
      bf16x8 af[2], bfv[2];
#pragma unroll
      for (int i = 0; i < 2; i++) {
        af[i]  = *reinterpret_cast<const bf16x8*>((const char*)sA + rowA[i] + chunkOff[s]);
        bfv[i] = *reinterpret_cast<const bf16x8*>((const char*)sB + rowB[i] + chunkOff[s]);
      }
#pragma unroll
      for (int i = 0; i < 2; i++)
#pragma unroll
        for (int j = 0; j < 2; j++)
          acc[i][j] = __builtin_amdgcn_mfma_f32_32x32x16_bf16(af[i], bfv[j], acc[i][j], 0, 0, 0);
    }
  }

  // ---- epilogue (verified layout: col = lane&31 -> n, row = (r&3)+8*(r>>2)+4*half) ----
  const int* mrow = (MODE == 2) ? (mask + (size_t)bz * 2048) : nullptr;
  const bool vblock = (MODE == 1) && (bx >= 16);  // QKV: n>=2048 is the V third
  float rs[2][16];  // MODE 2: per-lane partial row sums

#pragma unroll
  for (int i = 0; i < 2; i++) {
    int gmb = by * 128 + wm + i * 32;
    float inv_r[16];
    if (MODE == 3) {
#pragma unroll
      for (int r = 0; r < 16; r++) {
        int row = (r & 3) + 8 * (r >> 2) + 4 * half;
        inv_r[r] = 1.0f / sums[(size_t)bz * 2048 + gmb + row];
      }
    }
    if (MODE == 2) {
#pragma unroll
      for (int r = 0; r < 16; r++) rs[i][r] = 0.f;
    }
#pragma unroll
    for (int j = 0; j < 2; j++) {
      int gn = bx * 128 + wn + j * 32 + r31;
      float bv = (MODE == 0 || MODE == 1) ? bias[gn] : 0.0f;
      if (MODE == 1 && vblock) {
        // write V^T: Vt[b][d][s], d = gn-2048, s = gmb+row
        int b = gmb >> 11;
        int sbase = gmb & 2047;
        int d = gn - 2048;
        unsigned short* vp = vt + (size_t)b * 1024 * 2048 + (size_t)d * 2048 + sbase + 4 * half;
#pragma unroll
        for (int qd = 0; qd < 4; qd++) {
          ushort4 o;
          o.x = f2bf(acc[i][j][4 * qd + 0] + bv);
          o.y = f2bf(acc[i][j][4 * qd + 1] + bv);
          o.z = f2bf(acc[i][j][4 * qd + 2] + bv);
          o.w = f2bf(acc[i][j][4 * qd + 3] + bv);
          *reinterpret_cast<ushort4*>(vp + 8 * qd) = o;
        }
      } else {
        bool msk = (MODE == 2) ? (mrow[gn] == 0) : false;
#pragma unroll
        for (int r = 0; r < 16; r++) {
          int row = (r & 3) + 8 * (r >> 2) + 4 * half;
          float val = acc[i][j][r] + bv;
          size_t off = (size_t)bz * strideC + (size_t)(gmb + row) * ldc + gn;
          if (MODE == 2) {
            if (msk) val = -1e20f;
            val = __expf(val * 0.03125f);  // mask BEFORE 1/sqrt(1024) scale, per ref
            rs[i][r] += val;
            ((unsigned short*)Cv)[off] = f2bf(val);
          } else if (MODE == 3) {
            ((unsigned short*)Cv)[off] = f2bf(val * inv_r[r]);
          } else if (MODE == 1) {
            ((unsigned short*)Cv)[off] = f2bf(val);
          } else {
            ((float*)Cv)[off] = val;
          }
        }
      }
    }
  }

  if (MODE == 2) {
    // reduce rs over the 32 column-lanes (r31), then one atomicAdd per row.
    float* srow2 = sums + (size_t)bz * 2048;
#pragma unroll
    for (int i = 0; i < 2; i++) {
      int gmb = by * 128 + wm + i * 32;
#pragma unroll
      for (int r = 0; r < 16; r++) {
        float v = rs[i][r];
#pragma unroll
        for (int o = 16; o >= 1; o >>= 1) v += __shfl_xor(v, o, 64);
        if (r31 == 0) {
          int row = (r & 3) + 8 * (r >> 2) + 4 * half;
          atomicAdd(&srow2[gmb + row], v);
        }
      }
    }
  }
}

extern "C" void kernel_launch(void* const* d_in, const int* in_sizes, int n_in,
                              void* d_out, int out_size, void* d_ws, size_t ws_size,
                              hipStream_t stream) {
  const float* X = (const float*)d_in[0];
  const int* mask = (const int*)d_in[1];
  const float* W_in = (const float*)d_in[2];
  const float* b_in = (const float*)d_in[3];
  const float* W_out = (const float*)d_in[4];
  const float* b_out = (const float*)d_in[5];
  float* out = (float*)d_out;

  const int S = 2048, D = 1024;
  // ws layout (bytes):
  //   Xb  [8192x1024] bf16  16777216  (reused as Ob after QKV)
  //   Wib [3072x1024] bf16   6291456
  //   Wob [1024x1024] bf16   2097152
  //   QK  [8192x2048] bf16  33554432  (Q cols 0..1023, K cols 1024..2047)
  //   P   [4x2048x2048] bf16 33554432 (unnormalized exp weights)
  //   Vt  [4x1024x2048] bf16 16777216
  //   sums[8192] f32            32768
  char* w = (char*)d_ws;
  unsigned short* Xb  = (unsigned short*)w;
  unsigned short* Wib = (unsigned short*)(w + 16777216);
  unsigned short* Wob = (unsigned short*)(w + 16777216 + 6291456);
  unsigned short* QK  = (unsigned short*)(w + 25165824);
  unsigned short* P   = (unsigned short*)(w + 58720256);
  unsigned short* Vt  = (unsigned short*)(w + 92274688);
  float*          sums = (float*)(w + 109051904);
  unsigned short* Ob  = Xb;

  // zero the row-sum accumulators (ws is re-poisoned before every call)
  hipMemsetAsync(sums, 0, 8192 * sizeof(float), stream);

  // one merged cast: X, W_in, W_out -> bf16 (outputs contiguous), grid-stride
  cast_all_kernel<<<2048, 256, 0, stream>>>(X, W_in, W_out, Xb);

  // QKV = Xb @ W_in^T + b_in; Q,K -> QK[8192x2048], V -> Vt (transposed in epilogue)
  gemm_bt128<1><<<dim3(24, 64, 1), 256, 0, stream>>>(
      Xb, D, 0, Wib, D, 0, QK, 2048, 0, b_in, nullptr, nullptr, Vt, D);
  // P = exp(mask(Q K^T)/32); sums += row sums of fp32 exp  [per batch 2048x2048]
  gemm_bt128<2><<<dim3(16, 16, 4), 256, 0, stream>>>(
      QK, 2048, (long)S * 2048, QK + 1024, 2048, (long)S * 2048,
      P, S, (long)S * S, nullptr, mask, sums, nullptr, D);
  // O = (P @ Vt^T) / sums   [per batch 2048x1024] bf16
  gemm_bt128<3><<<dim3(8, 16, 4), 256, 0, stream>>>(
      P, S, (long)S * S, Vt, S, (long)D * S,
      Ob, D, (long)S * D, nullptr, nullptr, sums, nullptr, S);
  // out = O @ W_out^T + b_out  [8192x1024] fp32
  gemm_bt128<0><<<dim3(8, 64, 1), 256, 0, stream>>>(
      Ob, D, 0, Wob, D, 0, out, D, 0, b_out, nullptr, nullptr, nullptr, D);
}